// Round 7
// baseline (424.616 us; speedup 1.0000x reference)
//
#include <hip/hip_runtime.h>

typedef __attribute__((ext_vector_type(8))) short short8;   // 8 bf16 (MFMA A/B frag)
typedef __attribute__((ext_vector_type(4))) float floatx4;  // MFMA C/D frag

#define REGSZ 2400   // per-wave LDS region (dwords): hi[1200] + lo[1200]
#define LOOFF 1200

__device__ __forceinline__ float frcp(float x) { return __builtin_amdgcn_rcpf(x); }
__device__ __forceinline__ float fsigmoid(float x) { return frcp(1.f + __expf(-x)); }
__device__ __forceinline__ float fsoftplus(float x) {
    return fmaxf(x, 0.f) + __logf(1.f + __expf(-fabsf(x)));
}
__device__ __forceinline__ float felu(float x) { return x > 0.f ? x : __expf(x) - 1.f; }

// truncating fp32 -> (bf16 hi, bf16 lo) pair-pack: lo captures residual (err ~2^-17)
__device__ __forceinline__ void split2(float a0, float a1, unsigned& hi, unsigned& lo) {
    unsigned u0 = __float_as_uint(a0), u1 = __float_as_uint(a1);
    hi = (u0 >> 16) | (u1 & 0xffff0000u);
    float r0 = a0 - __uint_as_float(u0 & 0xffff0000u);
    float r1 = a1 - __uint_as_float(u1 & 0xffff0000u);
    lo = (__float_as_uint(r0) >> 16) | (__float_as_uint(r1) & 0xffff0000u);
}
__device__ __forceinline__ unsigned short f2bf_rne(float x) {
    unsigned u = __float_as_uint(x);
    u += 0x7fff + ((u >> 16) & 1);
    return (unsigned short)(u >> 16);
}
__device__ __forceinline__ float bf2f(unsigned short h) {
    return __uint_as_float(((unsigned)h) << 16);
}

// ---------------------------------------------------------------------------
// Kernel P: build MFMA B-fragments (bf16 hi/lo) for lin_w and edge_w|node_w.
// wfrag[((ver*2+nt)*5+s)*512 + lane*8 + j]; k=q*8+j -> tap=2s+(q>>1),
// cin=(q&1)*8+j; tap 9 (pad) -> 0.  lin: cout=nt*16+(lane&15).
// node: src = nt? node_w : edge_w; cout = lane&15.
// ---------------------------------------------------------------------------
__global__ __launch_bounds__(256) void prep_kernel(
    const float* __restrict__ edge_w, const float* __restrict__ node_w,
    const float* __restrict__ lin_w,
    short* __restrict__ wfrag_lin, short* __restrict__ wfrag_node)
{
    const int t = threadIdx.x;
    for (int i = t; i < 10240; i += 256) {
        int idx = i;
        int j = idx & 7; idx >>= 3;
        int lane = idx & 63; idx >>= 6;
        int s = idx % 5; idx /= 5;
        int nt = idx & 1;
        int ver = idx >> 1;
        int q = lane >> 4;
        int tap = 2 * s + (q >> 1);
        int cin = (q & 1) * 8 + j;
        {
            int cout = nt * 16 + (lane & 15);
            float v = (tap < 9) ? lin_w[cout * 144 + cin * 9 + tap] : 0.f;
            unsigned short hi = f2bf_rne(v);
            wfrag_lin[i] = (short)(ver ? f2bf_rne(v - bf2f(hi)) : hi);
        }
        {
            int cout = lane & 15;
            const float* src = nt ? node_w : edge_w;
            float v = (tap < 9) ? src[cout * 144 + cin * 9 + tap] : 0.f;
            unsigned short hi = f2bf_rne(v);
            wfrag_node[i] = (short)(ver ? f2bf_rne(v - bf2f(hi)) : hi);
        }
    }
}

// ---------------------------------------------------------------------------
// Binning: histogram -> exclusive scan -> scatter
// ---------------------------------------------------------------------------
__global__ __launch_bounds__(256) void hist_kernel(
    const int* __restrict__ esrc, int* __restrict__ counts, int E)
{
    int i = blockIdx.x * 256 + threadIdx.x;
    if (i < E) atomicAdd(&counts[esrc[i]], 1);
}

__global__ __launch_bounds__(256) void scan_kernel(
    const int* __restrict__ counts, int* __restrict__ offsets, int N)
{
    __shared__ int part[256];
    const int t = threadIdx.x;
    const int chunk = (N + 255) / 256;
    const int base = t * chunk;
    int s = 0;
    for (int i = 0; i < chunk; ++i) {
        int idx = base + i;
        if (idx < N) s += counts[idx];
    }
    part[t] = s;
    __syncthreads();
    for (int d = 1; d < 256; d <<= 1) {
        int v = (t >= d) ? part[t - d] : 0;
        __syncthreads();
        part[t] += v;
        __syncthreads();
    }
    int excl = (t == 0) ? 0 : part[t - 1];
    for (int i = 0; i < chunk; ++i) {
        int idx = base + i;
        if (idx < N) { offsets[idx] = excl; excl += counts[idx]; }
    }
    if (t == 255) offsets[N] = excl;
}

__global__ __launch_bounds__(256) void scatter_kernel(
    const int* __restrict__ esrc, const int* __restrict__ etgt,
    const int* __restrict__ offsets, int* __restrict__ cursor,
    int* __restrict__ bucket_tgt, int E)
{
    int i = blockIdx.x * 256 + threadIdx.x;
    if (i < E) {
        int s = esrc[i];
        int pos = atomicAdd(&cursor[s], 1);
        bucket_tgt[offsets[s] + pos] = etgt[i];
    }
}

// ---------------------------------------------------------------------------
// Kernel A: node convs via MFMA, wave-private (1 wave = 1 node), no barriers.
// zc = conv3x3(atom, edge_w), nc = conv3x3(atom, node_w).
// ---------------------------------------------------------------------------
__global__ __launch_bounds__(256, 4) void node_conv_kernel(
    const float* __restrict__ atom, const short* __restrict__ wfrag_node,
    float* __restrict__ zc, float* __restrict__ nc, int N)
{
    __shared__ unsigned zbuf[4 * REGSZ];     // 38.4 KB
    const int t = threadIdx.x;
    const int lane = t & 63;
    const int wv = t >> 6;
    const int n = blockIdx.x * 4 + wv;
    if (n >= N) return;                      // no barriers in this kernel
    unsigned* zb = &zbuf[wv * REGSZ];
    for (int i = lane; i < REGSZ; i += 64) zb[i] = 0u;

    const int c = lane & 15;                 // cout / A-row m
    const int q = lane >> 4;

    const short8* wf = (const short8*)wfrag_node;
    short8 W[2][2][5];
    #pragma unroll
    for (int v = 0; v < 2; ++v)
        #pragma unroll
        for (int nt = 0; nt < 2; ++nt)
            #pragma unroll
            for (int s = 0; s < 5; ++s)
                W[v][nt][s] = wf[(((v * 2) + nt) * 5 + s) * 64 + lane];

    int aoff[5];
    #pragma unroll
    for (int s = 0; s < 5; ++s) {
        int tap = 2 * s + (q >> 1);
        int ky = tap / 3, kx = tap - 3 * ky;
        // tap 9 = zero-padded K: B is 0, so A content is irrelevant -> clamp to 0
        aoff[s] = (tap < 9) ? ((((c >> 3) + ky) * 10 + (c & 7) + kx) * 12 + (q & 1) * 4) : 0;
    }

    const size_t nb = (size_t)n * 1024;
    float a[16];
    #pragma unroll
    for (int k = 0; k < 16; ++k) a[k] = atom[nb + k * 64 + lane];
    unsigned h[8], l[8];
    #pragma unroll
    for (int d = 0; d < 8; ++d) split2(a[2 * d], a[2 * d + 1], h[d], l[d]);
    const int sbase = (((lane >> 3) + 1) * 10 + (lane & 7) + 1) * 12;
    *(uint4*)&zb[sbase]     = make_uint4(h[0], h[1], h[2], h[3]);
    *(uint4*)&zb[sbase + 4] = make_uint4(h[4], h[5], h[6], h[7]);
    *(uint4*)&zb[LOOFF + sbase]     = make_uint4(l[0], l[1], l[2], l[3]);
    *(uint4*)&zb[LOOFF + sbase + 4] = make_uint4(l[4], l[5], l[6], l[7]);

    #pragma unroll
    for (int mt = 0; mt < 4; ++mt) {
        floatx4 ae = {0.f, 0.f, 0.f, 0.f}, an = {0.f, 0.f, 0.f, 0.f};
        const int mb = mt * 240;
        #pragma unroll
        for (int s = 0; s < 5; ++s) {
            short8 Ah = *(const short8*)&zb[mb * (aoff[s] != 0 || s < 5 ? 1 : 1) + aoff[s] + (aoff[s] ? 0 : 0)];
            // NOTE: for clamped taps (aoff==0) reading zb[mb+0] is also fine (border=0),
            // so keep the uniform expression:
            Ah = *(const short8*)&zb[mb + aoff[s]];
            short8 Al = *(const short8*)&zb[LOOFF + mb + aoff[s]];
            ae = __builtin_amdgcn_mfma_f32_16x16x32_bf16(Ah, W[0][0][s], ae, 0, 0, 0);
            an = __builtin_amdgcn_mfma_f32_16x16x32_bf16(Ah, W[0][1][s], an, 0, 0, 0);
            ae = __builtin_amdgcn_mfma_f32_16x16x32_bf16(Al, W[0][0][s], ae, 0, 0, 0);
            an = __builtin_amdgcn_mfma_f32_16x16x32_bf16(Al, W[0][1][s], an, 0, 0, 0);
            ae = __builtin_amdgcn_mfma_f32_16x16x32_bf16(Ah, W[1][0][s], ae, 0, 0, 0);
            an = __builtin_amdgcn_mfma_f32_16x16x32_bf16(Ah, W[1][1][s], an, 0, 0, 0);
        }
        *(floatx4*)&zc[nb + (size_t)c * 64 + mt * 16 + q * 4] = ae;
        *(floatx4*)&nc[nb + (size_t)c * 64 + mt * 16 + q * 4] = an;
    }
}

// ---------------------------------------------------------------------------
// Kernel B: node-major edge processing; 1 wave = 1 node, ALL its edges.
// No __syncthreads anywhere. Wave loops its node's edges: stage
// z = elu(nc[n]*zc[tgt]) into its own LDS region (bf16 hi/lo), 120 MFMA,
// fast sigmoid*softplus into register macc; fused BN/softplus epilogue.
// ---------------------------------------------------------------------------
__global__ __launch_bounds__(256, 4) void node_edge_kernel(
    const float* __restrict__ atom, const float* __restrict__ zc,
    const float* __restrict__ nc, const int* __restrict__ offsets,
    const int* __restrict__ bucket_tgt, const short* __restrict__ wfrag_lin,
    const float* __restrict__ lin_b, const float* __restrict__ gamma,
    const float* __restrict__ beta, float* __restrict__ out, int N)
{
    __shared__ unsigned zbuf[4 * REGSZ];     // 38.4 KB
    const int t = threadIdx.x;
    const int lane = t & 63;
    const int wv = t >> 6;
    const int n = blockIdx.x * 4 + wv;
    if (n >= N) return;
    const int c = lane & 15;
    const int q = lane >> 4;
    unsigned* zb = &zbuf[wv * REGSZ];
    for (int i = lane; i < REGSZ; i += 64) zb[i] = 0u;

    const short8* wf = (const short8*)wfrag_lin;
    short8 W[2][2][5];
    #pragma unroll
    for (int v = 0; v < 2; ++v)
        #pragma unroll
        for (int nt = 0; nt < 2; ++nt)
            #pragma unroll
            for (int s = 0; s < 5; ++s)
                W[v][nt][s] = wf[(((v * 2) + nt) * 5 + s) * 64 + lane];

    int aoff[5];
    #pragma unroll
    for (int s = 0; s < 5; ++s) {
        int tap = 2 * s + (q >> 1);
        int ky = tap / 3, kx = tap - 3 * ky;
        aoff[s] = (tap < 9) ? ((((c >> 3) + ky) * 10 + (c & 7) + kx) * 12 + (q & 1) * 4) : 0;
    }

    const size_t nb = (size_t)n * 1024;
    float nv[16];
    #pragma unroll
    for (int k = 0; k < 16; ++k) nv[k] = nc[nb + k * 64 + lane];
    const int sbase = (((lane >> 3) + 1) * 10 + (lane & 7) + 1) * 12;

    const int off = offsets[n];
    const int deg = offsets[n + 1] - off;

    const float bf = lin_b[c], bc = lin_b[c + 16];
    float macc[4][4] = {{0.f}};

    float zv[16];
    if (deg > 0) {
        const float* zp = zc + (size_t)bucket_tgt[off] * 1024;
        #pragma unroll
        for (int k = 0; k < 16; ++k) zv[k] = zp[k * 64 + lane];
    }

    for (int it = 0; it < deg; ++it) {
        float a[16];
        #pragma unroll
        for (int k = 0; k < 16; ++k) a[k] = felu(nv[k] * zv[k]);
        unsigned h[8], l[8];
        #pragma unroll
        for (int d = 0; d < 8; ++d) split2(a[2 * d], a[2 * d + 1], h[d], l[d]);
        *(uint4*)&zb[sbase]     = make_uint4(h[0], h[1], h[2], h[3]);
        *(uint4*)&zb[sbase + 4] = make_uint4(h[4], h[5], h[6], h[7]);
        *(uint4*)&zb[LOOFF + sbase]     = make_uint4(l[0], l[1], l[2], l[3]);
        *(uint4*)&zb[LOOFF + sbase + 4] = make_uint4(l[4], l[5], l[6], l[7]);

        if (it + 1 < deg) {                  // prefetch next edge during MFMA
            const float* zp = zc + (size_t)bucket_tgt[off + it + 1] * 1024;
            #pragma unroll
            for (int k = 0; k < 16; ++k) zv[k] = zp[k * 64 + lane];
        }

        #pragma unroll
        for (int mt = 0; mt < 4; ++mt) {
            floatx4 a0 = {0.f, 0.f, 0.f, 0.f}, a1 = {0.f, 0.f, 0.f, 0.f};
            const int mb = mt * 240;
            #pragma unroll
            for (int s = 0; s < 5; ++s) {
                short8 Ah = *(const short8*)&zb[mb + aoff[s]];
                short8 Al = *(const short8*)&zb[LOOFF + mb + aoff[s]];
                a0 = __builtin_amdgcn_mfma_f32_16x16x32_bf16(Ah, W[0][0][s], a0, 0, 0, 0);
                a1 = __builtin_amdgcn_mfma_f32_16x16x32_bf16(Ah, W[0][1][s], a1, 0, 0, 0);
                a0 = __builtin_amdgcn_mfma_f32_16x16x32_bf16(Al, W[0][0][s], a0, 0, 0, 0);
                a1 = __builtin_amdgcn_mfma_f32_16x16x32_bf16(Al, W[0][1][s], a1, 0, 0, 0);
                a0 = __builtin_amdgcn_mfma_f32_16x16x32_bf16(Ah, W[1][0][s], a0, 0, 0, 0);
                a1 = __builtin_amdgcn_mfma_f32_16x16x32_bf16(Ah, W[1][1][s], a1, 0, 0, 0);
            }
            #pragma unroll
            for (int r = 0; r < 4; ++r)
                macc[mt][r] += fsigmoid(a0[r] + bf) * fsoftplus(a1[r] + bc);
        }
    }

    // fused BN + softplus epilogue; pixel = mt*16 + q*4 + r, cout = c
    const float scale = gamma[c] * (1.f / sqrtf(1.f + 1e-5f));
    const float bet = beta[c];
    #pragma unroll
    for (int mt = 0; mt < 4; ++mt) {
        const size_t ob = nb + (size_t)c * 64 + mt * 16 + q * 4;
        const float4 av = *(const float4*)&atom[ob];
        float av4[4] = {av.x, av.y, av.z, av.w};
        float4 ov;
        float ov4[4];
        #pragma unroll
        for (int r = 0; r < 4; ++r) {
            float aa = av4[r];
            ov4[r] = fsoftplus(aa + (aa + macc[mt][r]) * scale + bet);
        }
        ov.x = ov4[0]; ov.y = ov4[1]; ov.z = ov4[2]; ov.w = ov4[3];
        *(float4*)&out[ob] = ov;
    }
}

extern "C" void kernel_launch(void* const* d_in, const int* in_sizes, int n_in,
                              void* d_out, int out_size, void* d_ws, size_t ws_size,
                              hipStream_t stream) {
    const float* atom   = (const float*)d_in[0];
    const int*   esrc   = (const int*)d_in[1];
    const int*   etgt   = (const int*)d_in[2];
    const float* edge_w = (const float*)d_in[3];
    const float* node_w = (const float*)d_in[4];
    const float* lin_w  = (const float*)d_in[5];
    const float* lin_b  = (const float*)d_in[6];
    const float* gamma  = (const float*)d_in[7];
    const float* beta   = (const float*)d_in[8];
    float* out = (float*)d_out;

    const int total = in_sizes[0];      // N*16*8*8
    const int N = total / 1024;         // 8000
    const int E = in_sizes[1];          // 48000

    char* wsb = (char*)d_ws;
    float* zcb       = (float*)wsb;                                   // total fp32
    float* ncb       = (float*)(wsb + (size_t)total * 4);             // total fp32
    short* wfrag_lin = (short*)(wsb + (size_t)total * 8);             // 10240 (16B-aligned)
    short* wfrag_nod = wfrag_lin + 10240;                             // 10240
    int*   counts    = (int*)(wfrag_nod + 10240);                     // N
    int*   cursor    = counts + N;                                    // N
    int*   offsets   = cursor + N;                                    // N+1
    int*   bucket    = offsets + N + 1;                               // E

    hipMemsetAsync(counts, 0, (size_t)2 * N * 4, stream);             // counts+cursor
    prep_kernel<<<1, 256, 0, stream>>>(edge_w, node_w, lin_w, wfrag_lin, wfrag_nod);
    hist_kernel<<<(E + 255) / 256, 256, 0, stream>>>(esrc, counts, E);
    scan_kernel<<<1, 256, 0, stream>>>(counts, offsets, N);
    scatter_kernel<<<(E + 255) / 256, 256, 0, stream>>>(esrc, etgt, offsets, cursor, bucket, E);
    node_conv_kernel<<<(N + 3) / 4, 256, 0, stream>>>(atom, wfrag_nod, zcb, ncb, N);
    node_edge_kernel<<<(N + 3) / 4, 256, 0, stream>>>(atom, zcb, ncb, offsets, bucket,
                                                      wfrag_lin, lin_b, gamma, beta, out, N);
}

// Round 8
// 289.146 us; speedup vs baseline: 1.4685x; 1.4685x over previous
//
#include <hip/hip_runtime.h>

typedef __attribute__((ext_vector_type(8))) short short8;   // 8 bf16 (MFMA A/B frag)
typedef __attribute__((ext_vector_type(4))) float floatx4;  // MFMA C/D frag

#define REGSZ 2400   // per-wave LDS region (dwords): hi[1200] + lo[1200]
#define LOOFF 1200

__device__ __forceinline__ float frcp(float x) { return __builtin_amdgcn_rcpf(x); }
__device__ __forceinline__ float fsigmoid(float x) { return frcp(1.f + __expf(-x)); }
__device__ __forceinline__ float fsoftplus(float x) {
    return fmaxf(x, 0.f) + __logf(1.f + __expf(-fabsf(x)));
}
__device__ __forceinline__ float felu(float x) { return x > 0.f ? x : __expf(x) - 1.f; }

// truncating fp32 -> (bf16 hi, bf16 lo) pair-pack: lo captures residual (err ~2^-17)
__device__ __forceinline__ void split2(float a0, float a1, unsigned& hi, unsigned& lo) {
    unsigned u0 = __float_as_uint(a0), u1 = __float_as_uint(a1);
    hi = (u0 >> 16) | (u1 & 0xffff0000u);
    float r0 = a0 - __uint_as_float(u0 & 0xffff0000u);
    float r1 = a1 - __uint_as_float(u1 & 0xffff0000u);
    lo = (__float_as_uint(r0) >> 16) | (__float_as_uint(r1) & 0xffff0000u);
}
__device__ __forceinline__ unsigned short f2bf_rne(float x) {
    unsigned u = __float_as_uint(x);
    u += 0x7fff + ((u >> 16) & 1);
    return (unsigned short)(u >> 16);
}
__device__ __forceinline__ float bf2f(unsigned short h) {
    return __uint_as_float(((unsigned)h) << 16);
}

// ---------------------------------------------------------------------------
// Kernel P: build MFMA B-fragments (bf16 hi/lo) for lin_w and edge_w|node_w.
// wfrag[((ver*2+nt)*5+s)*512 + lane*8 + j]; k=q*8+j -> tap=2s+(q>>1),
// cin=(q&1)*8+j; tap 9 (pad) -> 0.  lin: cout=nt*16+(lane&15).
// node: src = nt? node_w : edge_w; cout = lane&15.
// ---------------------------------------------------------------------------
__global__ __launch_bounds__(256) void prep_kernel(
    const float* __restrict__ edge_w, const float* __restrict__ node_w,
    const float* __restrict__ lin_w,
    short* __restrict__ wfrag_lin, short* __restrict__ wfrag_node)
{
    const int t = threadIdx.x;
    for (int i = t; i < 10240; i += 256) {
        int idx = i;
        int j = idx & 7; idx >>= 3;
        int lane = idx & 63; idx >>= 6;
        int s = idx % 5; idx /= 5;
        int nt = idx & 1;
        int ver = idx >> 1;
        int q = lane >> 4;
        int tap = 2 * s + (q >> 1);
        int cin = (q & 1) * 8 + j;
        {
            int cout = nt * 16 + (lane & 15);
            float v = (tap < 9) ? lin_w[cout * 144 + cin * 9 + tap] : 0.f;
            unsigned short hi = f2bf_rne(v);
            wfrag_lin[i] = (short)(ver ? f2bf_rne(v - bf2f(hi)) : hi);
        }
        {
            int cout = lane & 15;
            const float* src = nt ? node_w : edge_w;
            float v = (tap < 9) ? src[cout * 144 + cin * 9 + tap] : 0.f;
            unsigned short hi = f2bf_rne(v);
            wfrag_node[i] = (short)(ver ? f2bf_rne(v - bf2f(hi)) : hi);
        }
    }
}

// ---------------------------------------------------------------------------
// Binning: histogram -> exclusive scan -> scatter
// ---------------------------------------------------------------------------
__global__ __launch_bounds__(256) void hist_kernel(
    const int* __restrict__ esrc, int* __restrict__ counts, int E)
{
    int i = blockIdx.x * 256 + threadIdx.x;
    if (i < E) atomicAdd(&counts[esrc[i]], 1);
}

__global__ __launch_bounds__(256) void scan_kernel(
    const int* __restrict__ counts, int* __restrict__ offsets, int N)
{
    __shared__ int part[256];
    const int t = threadIdx.x;
    const int chunk = (N + 255) / 256;
    const int base = t * chunk;
    int s = 0;
    for (int i = 0; i < chunk; ++i) {
        int idx = base + i;
        if (idx < N) s += counts[idx];
    }
    part[t] = s;
    __syncthreads();
    for (int d = 1; d < 256; d <<= 1) {
        int v = (t >= d) ? part[t - d] : 0;
        __syncthreads();
        part[t] += v;
        __syncthreads();
    }
    int excl = (t == 0) ? 0 : part[t - 1];
    for (int i = 0; i < chunk; ++i) {
        int idx = base + i;
        if (idx < N) { offsets[idx] = excl; excl += counts[idx]; }
    }
    if (t == 255) offsets[N] = excl;
}

__global__ __launch_bounds__(256) void scatter_kernel(
    const int* __restrict__ esrc, const int* __restrict__ etgt,
    const int* __restrict__ offsets, int* __restrict__ cursor,
    int* __restrict__ bucket_tgt, int E)
{
    int i = blockIdx.x * 256 + threadIdx.x;
    if (i < E) {
        int s = esrc[i];
        int pos = atomicAdd(&cursor[s], 1);
        bucket_tgt[offsets[s] + pos] = etgt[i];
    }
}

// ---------------------------------------------------------------------------
// Kernel A: node convs via MFMA, wave-private (1 wave = 1 node), no barriers.
// zc = conv3x3(atom, edge_w), nc = conv3x3(atom, node_w).
// launch_bounds(256,3): VGPR cap 168 — R7's (256,4) capped at 64 and spilled
// ~840 MB/dispatch to scratch (FETCH 578 MB, WRITE 417 MB). Never again.
// ---------------------------------------------------------------------------
__global__ __launch_bounds__(256, 3) void node_conv_kernel(
    const float* __restrict__ atom, const short* __restrict__ wfrag_node,
    float* __restrict__ zc, float* __restrict__ nc, int N)
{
    __shared__ unsigned zbuf[4 * REGSZ];     // 38.4 KB
    const int t = threadIdx.x;
    const int lane = t & 63;
    const int wv = t >> 6;
    const int n = blockIdx.x * 4 + wv;
    if (n >= N) return;                      // no barriers in this kernel
    unsigned* zb = &zbuf[wv * REGSZ];
    for (int i = lane; i < REGSZ; i += 64) zb[i] = 0u;

    const int c = lane & 15;                 // cout / A-row m
    const int q = lane >> 4;

    const short8* wf = (const short8*)wfrag_node;
    short8 W[2][2][5];
    #pragma unroll
    for (int v = 0; v < 2; ++v)
        #pragma unroll
        for (int nt = 0; nt < 2; ++nt)
            #pragma unroll
            for (int s = 0; s < 5; ++s)
                W[v][nt][s] = wf[(((v * 2) + nt) * 5 + s) * 64 + lane];

    int aoff[5];
    #pragma unroll
    for (int s = 0; s < 5; ++s) {
        int tap = 2 * s + (q >> 1);
        int ky = tap / 3, kx = tap - 3 * ky;
        // tap 9 = zero-padded K: B is 0, so A content is irrelevant -> clamp to 0
        aoff[s] = (tap < 9) ? ((((c >> 3) + ky) * 10 + (c & 7) + kx) * 12 + (q & 1) * 4) : 0;
    }

    const size_t nb = (size_t)n * 1024;
    float a[16];
    #pragma unroll
    for (int k = 0; k < 16; ++k) a[k] = atom[nb + k * 64 + lane];
    unsigned h[8], l[8];
    #pragma unroll
    for (int d = 0; d < 8; ++d) split2(a[2 * d], a[2 * d + 1], h[d], l[d]);
    const int sbase = (((lane >> 3) + 1) * 10 + (lane & 7) + 1) * 12;
    *(uint4*)&zb[sbase]     = make_uint4(h[0], h[1], h[2], h[3]);
    *(uint4*)&zb[sbase + 4] = make_uint4(h[4], h[5], h[6], h[7]);
    *(uint4*)&zb[LOOFF + sbase]     = make_uint4(l[0], l[1], l[2], l[3]);
    *(uint4*)&zb[LOOFF + sbase + 4] = make_uint4(l[4], l[5], l[6], l[7]);

    #pragma unroll
    for (int mt = 0; mt < 4; ++mt) {
        floatx4 ae = {0.f, 0.f, 0.f, 0.f}, an = {0.f, 0.f, 0.f, 0.f};
        const int mb = mt * 240;
        #pragma unroll
        for (int s = 0; s < 5; ++s) {
            short8 Ah = *(const short8*)&zb[mb + aoff[s]];
            short8 Al = *(const short8*)&zb[LOOFF + mb + aoff[s]];
            ae = __builtin_amdgcn_mfma_f32_16x16x32_bf16(Ah, W[0][0][s], ae, 0, 0, 0);
            an = __builtin_amdgcn_mfma_f32_16x16x32_bf16(Ah, W[0][1][s], an, 0, 0, 0);
            ae = __builtin_amdgcn_mfma_f32_16x16x32_bf16(Al, W[0][0][s], ae, 0, 0, 0);
            an = __builtin_amdgcn_mfma_f32_16x16x32_bf16(Al, W[0][1][s], an, 0, 0, 0);
            ae = __builtin_amdgcn_mfma_f32_16x16x32_bf16(Ah, W[1][0][s], ae, 0, 0, 0);
            an = __builtin_amdgcn_mfma_f32_16x16x32_bf16(Ah, W[1][1][s], an, 0, 0, 0);
        }
        *(floatx4*)&zc[nb + (size_t)c * 64 + mt * 16 + q * 4] = ae;
        *(floatx4*)&nc[nb + (size_t)c * 64 + mt * 16 + q * 4] = an;
    }
}

// ---------------------------------------------------------------------------
// Kernel B: node-major edge processing; 1 wave = 1 node, ALL its edges.
// No __syncthreads anywhere. Wave loops its node's edges: stage
// z = elu(nc[n]*zc[tgt]) into its own LDS region (bf16 hi/lo), 120 MFMA,
// fast sigmoid*softplus into register macc; fused BN/softplus epilogue.
// ---------------------------------------------------------------------------
__global__ __launch_bounds__(256, 3) void node_edge_kernel(
    const float* __restrict__ atom, const float* __restrict__ zc,
    const float* __restrict__ nc, const int* __restrict__ offsets,
    const int* __restrict__ bucket_tgt, const short* __restrict__ wfrag_lin,
    const float* __restrict__ lin_b, const float* __restrict__ gamma,
    const float* __restrict__ beta, float* __restrict__ out, int N)
{
    __shared__ unsigned zbuf[4 * REGSZ];     // 38.4 KB
    const int t = threadIdx.x;
    const int lane = t & 63;
    const int wv = t >> 6;
    const int n = blockIdx.x * 4 + wv;
    if (n >= N) return;
    const int c = lane & 15;
    const int q = lane >> 4;
    unsigned* zb = &zbuf[wv * REGSZ];
    for (int i = lane; i < REGSZ; i += 64) zb[i] = 0u;

    const short8* wf = (const short8*)wfrag_lin;
    short8 W[2][2][5];
    #pragma unroll
    for (int v = 0; v < 2; ++v)
        #pragma unroll
        for (int nt = 0; nt < 2; ++nt)
            #pragma unroll
            for (int s = 0; s < 5; ++s)
                W[v][nt][s] = wf[(((v * 2) + nt) * 5 + s) * 64 + lane];

    int aoff[5];
    #pragma unroll
    for (int s = 0; s < 5; ++s) {
        int tap = 2 * s + (q >> 1);
        int ky = tap / 3, kx = tap - 3 * ky;
        aoff[s] = (tap < 9) ? ((((c >> 3) + ky) * 10 + (c & 7) + kx) * 12 + (q & 1) * 4) : 0;
    }

    const size_t nb = (size_t)n * 1024;
    float nv[16];
    #pragma unroll
    for (int k = 0; k < 16; ++k) nv[k] = nc[nb + k * 64 + lane];
    const int sbase = (((lane >> 3) + 1) * 10 + (lane & 7) + 1) * 12;

    const int off = offsets[n];
    const int deg = offsets[n + 1] - off;

    const float bf = lin_b[c], bc = lin_b[c + 16];
    float macc[4][4] = {{0.f}};

    float zv[16];
    if (deg > 0) {
        const float* zp = zc + (size_t)bucket_tgt[off] * 1024;
        #pragma unroll
        for (int k = 0; k < 16; ++k) zv[k] = zp[k * 64 + lane];
    }

    for (int it = 0; it < deg; ++it) {
        float a[16];
        #pragma unroll
        for (int k = 0; k < 16; ++k) a[k] = felu(nv[k] * zv[k]);
        unsigned h[8], l[8];
        #pragma unroll
        for (int d = 0; d < 8; ++d) split2(a[2 * d], a[2 * d + 1], h[d], l[d]);
        *(uint4*)&zb[sbase]     = make_uint4(h[0], h[1], h[2], h[3]);
        *(uint4*)&zb[sbase + 4] = make_uint4(h[4], h[5], h[6], h[7]);
        *(uint4*)&zb[LOOFF + sbase]     = make_uint4(l[0], l[1], l[2], l[3]);
        *(uint4*)&zb[LOOFF + sbase + 4] = make_uint4(l[4], l[5], l[6], l[7]);

        if (it + 1 < deg) {                  // prefetch next edge during MFMA
            const float* zp = zc + (size_t)bucket_tgt[off + it + 1] * 1024;
            #pragma unroll
            for (int k = 0; k < 16; ++k) zv[k] = zp[k * 64 + lane];
        }

        #pragma unroll
        for (int mt = 0; mt < 4; ++mt) {
            floatx4 a0 = {0.f, 0.f, 0.f, 0.f}, a1 = {0.f, 0.f, 0.f, 0.f};
            const int mb = mt * 240;
            #pragma unroll
            for (int s = 0; s < 5; ++s) {
                short8 Ah = *(const short8*)&zb[mb + aoff[s]];
                short8 Al = *(const short8*)&zb[LOOFF + mb + aoff[s]];
                a0 = __builtin_amdgcn_mfma_f32_16x16x32_bf16(Ah, W[0][0][s], a0, 0, 0, 0);
                a1 = __builtin_amdgcn_mfma_f32_16x16x32_bf16(Ah, W[0][1][s], a1, 0, 0, 0);
                a0 = __builtin_amdgcn_mfma_f32_16x16x32_bf16(Al, W[0][0][s], a0, 0, 0, 0);
                a1 = __builtin_amdgcn_mfma_f32_16x16x32_bf16(Al, W[0][1][s], a1, 0, 0, 0);
                a0 = __builtin_amdgcn_mfma_f32_16x16x32_bf16(Ah, W[1][0][s], a0, 0, 0, 0);
                a1 = __builtin_amdgcn_mfma_f32_16x16x32_bf16(Ah, W[1][1][s], a1, 0, 0, 0);
            }
            #pragma unroll
            for (int r = 0; r < 4; ++r)
                macc[mt][r] += fsigmoid(a0[r] + bf) * fsoftplus(a1[r] + bc);
        }
    }

    // fused BN + softplus epilogue; pixel = mt*16 + q*4 + r, cout = c
    const float scale = gamma[c] * (1.f / sqrtf(1.f + 1e-5f));
    const float bet = beta[c];
    #pragma unroll
    for (int mt = 0; mt < 4; ++mt) {
        const size_t ob = nb + (size_t)c * 64 + mt * 16 + q * 4;
        const float4 av = *(const float4*)&atom[ob];
        float av4[4] = {av.x, av.y, av.z, av.w};
        float4 ov;
        float ov4[4];
        #pragma unroll
        for (int r = 0; r < 4; ++r) {
            float aa = av4[r];
            ov4[r] = fsoftplus(aa + (aa + macc[mt][r]) * scale + bet);
        }
        ov.x = ov4[0]; ov.y = ov4[1]; ov.z = ov4[2]; ov.w = ov4[3];
        *(float4*)&out[ob] = ov;
    }
}

extern "C" void kernel_launch(void* const* d_in, const int* in_sizes, int n_in,
                              void* d_out, int out_size, void* d_ws, size_t ws_size,
                              hipStream_t stream) {
    const float* atom   = (const float*)d_in[0];
    const int*   esrc   = (const int*)d_in[1];
    const int*   etgt   = (const int*)d_in[2];
    const float* edge_w = (const float*)d_in[3];
    const float* node_w = (const float*)d_in[4];
    const float* lin_w  = (const float*)d_in[5];
    const float* lin_b  = (const float*)d_in[6];
    const float* gamma  = (const float*)d_in[7];
    const float* beta   = (const float*)d_in[8];
    float* out = (float*)d_out;

    const int total = in_sizes[0];      // N*16*8*8
    const int N = total / 1024;         // 8000
    const int E = in_sizes[1];          // 48000

    char* wsb = (char*)d_ws;
    float* zcb       = (float*)wsb;                                   // total fp32
    float* ncb       = (float*)(wsb + (size_t)total * 4);             // total fp32
    short* wfrag_lin = (short*)(wsb + (size_t)total * 8);             // 10240 (16B-aligned)
    short* wfrag_nod = wfrag_lin + 10240;                             // 10240
    int*   counts    = (int*)(wfrag_nod + 10240);                     // N
    int*   cursor    = counts + N;                                    // N
    int*   offsets   = cursor + N;                                    // N+1
    int*   bucket    = offsets + N + 1;                               // E

    hipMemsetAsync(counts, 0, (size_t)2 * N * 4, stream);             // counts+cursor
    prep_kernel<<<1, 256, 0, stream>>>(edge_w, node_w, lin_w, wfrag_lin, wfrag_nod);
    hist_kernel<<<(E + 255) / 256, 256, 0, stream>>>(esrc, counts, E);
    scan_kernel<<<1, 256, 0, stream>>>(counts, offsets, N);
    scatter_kernel<<<(E + 255) / 256, 256, 0, stream>>>(esrc, etgt, offsets, cursor, bucket, E);
    node_conv_kernel<<<(N + 3) / 4, 256, 0, stream>>>(atom, wfrag_nod, zcb, ncb, N);
    node_edge_kernel<<<(N + 3) / 4, 256, 0, stream>>>(atom, zcb, ncb, offsets, bucket,
                                                      wfrag_lin, lin_b, gamma, beta, out, N);
}

// Round 9
// 270.682 us; speedup vs baseline: 1.5687x; 1.0682x over previous
//
#include <hip/hip_runtime.h>

typedef __attribute__((ext_vector_type(8))) short short8;   // 8 bf16 (MFMA A/B frag)
typedef __attribute__((ext_vector_type(4))) float floatx4;  // MFMA C/D frag

// per-wave LDS region: 100 pixels x 20 dwords (hi[8] | lo[8] | pad[4])
// pitch 20 dwords = 80 B: 16B-aligned and (20*pix)%32 covers all bank groups.
#define PITCH 20
#define REGSZ 2000

__device__ __forceinline__ float frcp(float x) { return __builtin_amdgcn_rcpf(x); }
__device__ __forceinline__ float fsigmoid(float x) { return frcp(1.f + __expf(-x)); }
__device__ __forceinline__ float fsoftplus(float x) {
    return fmaxf(x, 0.f) + __logf(1.f + __expf(-fabsf(x)));
}
__device__ __forceinline__ float felu(float x) { return x > 0.f ? x : __expf(x) - 1.f; }

// truncating fp32 -> (bf16 hi, bf16 lo) pair-pack: lo captures residual (err ~2^-17)
__device__ __forceinline__ void split2(float a0, float a1, unsigned& hi, unsigned& lo) {
    unsigned u0 = __float_as_uint(a0), u1 = __float_as_uint(a1);
    hi = (u0 >> 16) | (u1 & 0xffff0000u);
    float r0 = a0 - __uint_as_float(u0 & 0xffff0000u);
    float r1 = a1 - __uint_as_float(u1 & 0xffff0000u);
    lo = (__float_as_uint(r0) >> 16) | (__float_as_uint(r1) & 0xffff0000u);
}
__device__ __forceinline__ unsigned short f2bf_rne(float x) {
    unsigned u = __float_as_uint(x);
    u += 0x7fff + ((u >> 16) & 1);
    return (unsigned short)(u >> 16);
}
__device__ __forceinline__ float bf2f(unsigned short h) {
    return __uint_as_float(((unsigned)h) << 16);
}

// ---------------------------------------------------------------------------
// K1: prep (block 188) + edge-source histogram (blocks 0..187).
// ---------------------------------------------------------------------------
__global__ __launch_bounds__(256) void prep_hist_kernel(
    const float* __restrict__ edge_w, const float* __restrict__ node_w,
    const float* __restrict__ lin_w, const int* __restrict__ esrc,
    short* __restrict__ wfrag_lin, short* __restrict__ wfrag_node,
    int* __restrict__ counts, int E, int nhist)
{
    const int t = threadIdx.x;
    if ((int)blockIdx.x < nhist) {
        int i = blockIdx.x * 256 + t;
        if (i < E) atomicAdd(&counts[esrc[i]], 1);
        return;
    }
    // prep: MFMA B-fragments (bf16 hi/lo) for lin_w and edge_w|node_w
    for (int i = t; i < 10240; i += 256) {
        int idx = i;
        int j = idx & 7; idx >>= 3;
        int lane = idx & 63; idx >>= 6;
        int s = idx % 5; idx /= 5;
        int nt = idx & 1;
        int ver = idx >> 1;
        int q = lane >> 4;
        int tap = 2 * s + (q >> 1);
        int cin = (q & 1) * 8 + j;
        {
            int cout = nt * 16 + (lane & 15);
            float v = (tap < 9) ? lin_w[cout * 144 + cin * 9 + tap] : 0.f;
            unsigned short hi = f2bf_rne(v);
            wfrag_lin[i] = (short)(ver ? f2bf_rne(v - bf2f(hi)) : hi);
        }
        {
            int cout = lane & 15;
            const float* src = nt ? node_w : edge_w;
            float v = (tap < 9) ? src[cout * 144 + cin * 9 + tap] : 0.f;
            unsigned short hi = f2bf_rne(v);
            wfrag_node[i] = (short)(ver ? f2bf_rne(v - bf2f(hi)) : hi);
        }
    }
}

// ---------------------------------------------------------------------------
// K2: exclusive scan of per-node edge counts (single block).
// ---------------------------------------------------------------------------
__global__ __launch_bounds__(256) void scan_kernel(
    const int* __restrict__ counts, int* __restrict__ offsets, int N)
{
    __shared__ int part[256];
    const int t = threadIdx.x;
    const int chunk = (N + 255) / 256;
    const int base = t * chunk;
    int s = 0;
    for (int i = 0; i < chunk; ++i) {
        int idx = base + i;
        if (idx < N) s += counts[idx];
    }
    part[t] = s;
    __syncthreads();
    for (int d = 1; d < 256; d <<= 1) {
        int v = (t >= d) ? part[t - d] : 0;
        __syncthreads();
        part[t] += v;
        __syncthreads();
    }
    int excl = (t == 0) ? 0 : part[t - 1];
    for (int i = 0; i < chunk; ++i) {
        int idx = base + i;
        if (idx < N) { offsets[idx] = excl; excl += counts[idx]; }
    }
    if (t == 255) offsets[N] = excl;
}

// ---------------------------------------------------------------------------
// K3: node convs via MFMA (blocks < nconv) + edge scatter (next nscat blocks)
//     + degree-descending node order (last block).
// ---------------------------------------------------------------------------
__global__ __launch_bounds__(256, 3) void conv_scatter_order_kernel(
    const float* __restrict__ atom, const short* __restrict__ wfrag_node,
    float* __restrict__ zc, float* __restrict__ nc,
    const int* __restrict__ esrc, const int* __restrict__ etgt,
    const int* __restrict__ offsets, int* __restrict__ cursor,
    int* __restrict__ bucket_tgt, int* __restrict__ nlist,
    int N, int E, int nconv, int nscat)
{
    __shared__ unsigned zbuf[4 * REGSZ];     // 32 KB (conv part only)
    __shared__ int bh[64], bo[64];           // order part
    const int t = threadIdx.x;
    const int b = blockIdx.x;

    if (b >= nconv + nscat) {
        // ----- order: counting sort of nodes by degree, DESCENDING -----
        if (t < 64) bh[t] = 0;
        __syncthreads();
        for (int n = t; n < N; n += 256) {
            int deg = offsets[n + 1] - offsets[n];
            atomicAdd(&bh[min(deg, 63)], 1);
        }
        __syncthreads();
        if (t == 0) {
            int run = 0;
            for (int d = 63; d >= 0; --d) { bo[d] = run; run += bh[d]; }
        }
        __syncthreads();
        for (int n = t; n < N; n += 256) {
            int deg = offsets[n + 1] - offsets[n];
            int pos = atomicAdd(&bo[min(deg, 63)], 1);
            nlist[pos] = n;
        }
        return;
    }
    if (b >= nconv) {
        // ----- scatter: bucket edge targets by source -----
        int i = (b - nconv) * 256 + t;
        if (i < E) {
            int s = esrc[i];
            int pos = atomicAdd(&cursor[s], 1);
            bucket_tgt[offsets[s] + pos] = etgt[i];
        }
        return;
    }

    // ----- conv: 1 wave = 1 node, no barriers -----
    const int lane = t & 63;
    const int wv = t >> 6;
    const int n = b * 4 + wv;
    if (n >= N) return;
    unsigned* zb = &zbuf[wv * REGSZ];
    for (int i = lane; i < REGSZ; i += 64) zb[i] = 0u;

    const int c = lane & 15;
    const int q = lane >> 4;

    const short8* wf = (const short8*)wfrag_node;
    short8 W[2][2][5];
    #pragma unroll
    for (int v = 0; v < 2; ++v)
        #pragma unroll
        for (int nt = 0; nt < 2; ++nt)
            #pragma unroll
            for (int s = 0; s < 5; ++s)
                W[v][nt][s] = wf[(((v * 2) + nt) * 5 + s) * 64 + lane];

    int aoff[5];
    #pragma unroll
    for (int s = 0; s < 5; ++s) {
        int tap = 2 * s + (q >> 1);
        int ky = tap / 3, kx = tap - 3 * ky;
        aoff[s] = (tap < 9) ? ((((c >> 3) + ky) * 10 + (c & 7) + kx) * PITCH + (q & 1) * 4) : 0;
    }

    const size_t nb = (size_t)n * 1024;
    float a[16];
    #pragma unroll
    for (int k = 0; k < 16; ++k) a[k] = atom[nb + k * 64 + lane];
    unsigned h[8], l[8];
    #pragma unroll
    for (int d = 0; d < 8; ++d) split2(a[2 * d], a[2 * d + 1], h[d], l[d]);
    const int sbase = (((lane >> 3) + 1) * 10 + (lane & 7) + 1) * PITCH;
    *(uint4*)&zb[sbase]      = make_uint4(h[0], h[1], h[2], h[3]);
    *(uint4*)&zb[sbase + 4]  = make_uint4(h[4], h[5], h[6], h[7]);
    *(uint4*)&zb[sbase + 8]  = make_uint4(l[0], l[1], l[2], l[3]);
    *(uint4*)&zb[sbase + 12] = make_uint4(l[4], l[5], l[6], l[7]);

    #pragma unroll
    for (int mt = 0; mt < 4; ++mt) {
        floatx4 ae = {0.f, 0.f, 0.f, 0.f}, an = {0.f, 0.f, 0.f, 0.f};
        const int mb = mt * 2 * 10 * PITCH;
        #pragma unroll
        for (int s = 0; s < 5; ++s) {
            short8 Ah = *(const short8*)&zb[mb + aoff[s]];
            short8 Al = *(const short8*)&zb[mb + aoff[s] + 8];
            ae = __builtin_amdgcn_mfma_f32_16x16x32_bf16(Ah, W[0][0][s], ae, 0, 0, 0);
            an = __builtin_amdgcn_mfma_f32_16x16x32_bf16(Ah, W[0][1][s], an, 0, 0, 0);
            ae = __builtin_amdgcn_mfma_f32_16x16x32_bf16(Al, W[0][0][s], ae, 0, 0, 0);
            an = __builtin_amdgcn_mfma_f32_16x16x32_bf16(Al, W[0][1][s], an, 0, 0, 0);
            ae = __builtin_amdgcn_mfma_f32_16x16x32_bf16(Ah, W[1][0][s], ae, 0, 0, 0);
            an = __builtin_amdgcn_mfma_f32_16x16x32_bf16(Ah, W[1][1][s], an, 0, 0, 0);
        }
        *(floatx4*)&zc[nb + (size_t)c * 64 + mt * 16 + q * 4] = ae;
        *(floatx4*)&nc[nb + (size_t)c * 64 + mt * 16 + q * 4] = an;
    }
}

// ---------------------------------------------------------------------------
// K4: node-major edge processing; 1 wave = 1 node (degree-sorted via nlist).
// No __syncthreads. stage z=elu(nc[n]*zc[tgt]) -> LDS (bf16 hi/lo, pitch 20),
// 120 MFMA, fast sigmoid*softplus into register macc; fused BN/softplus.
// launch_bounds(256,3): VGPR cap 168 — (256,4) capped 64 and spilled (R7).
// ---------------------------------------------------------------------------
__global__ __launch_bounds__(256, 3) void node_edge_kernel(
    const float* __restrict__ atom, const float* __restrict__ zc,
    const float* __restrict__ nc, const int* __restrict__ offsets,
    const int* __restrict__ bucket_tgt, const int* __restrict__ nlist,
    const short* __restrict__ wfrag_lin, const float* __restrict__ lin_b,
    const float* __restrict__ gamma, const float* __restrict__ beta,
    float* __restrict__ out, int N)
{
    __shared__ unsigned zbuf[4 * REGSZ];     // 32 KB
    const int t = threadIdx.x;
    const int lane = t & 63;
    const int wv = t >> 6;
    const int ni = blockIdx.x * 4 + wv;
    if (ni >= N) return;
    const int n = nlist[ni];
    const int c = lane & 15;
    const int q = lane >> 4;
    unsigned* zb = &zbuf[wv * REGSZ];
    for (int i = lane; i < REGSZ; i += 64) zb[i] = 0u;

    const short8* wf = (const short8*)wfrag_lin;
    short8 W[2][2][5];
    #pragma unroll
    for (int v = 0; v < 2; ++v)
        #pragma unroll
        for (int nt = 0; nt < 2; ++nt)
            #pragma unroll
            for (int s = 0; s < 5; ++s)
                W[v][nt][s] = wf[(((v * 2) + nt) * 5 + s) * 64 + lane];

    int aoff[5];
    #pragma unroll
    for (int s = 0; s < 5; ++s) {
        int tap = 2 * s + (q >> 1);
        int ky = tap / 3, kx = tap - 3 * ky;
        aoff[s] = (tap < 9) ? ((((c >> 3) + ky) * 10 + (c & 7) + kx) * PITCH + (q & 1) * 4) : 0;
    }

    const size_t nb = (size_t)n * 1024;
    float nv[16];
    #pragma unroll
    for (int k = 0; k < 16; ++k) nv[k] = nc[nb + k * 64 + lane];
    const int sbase = (((lane >> 3) + 1) * 10 + (lane & 7) + 1) * PITCH;

    const int off = offsets[n];
    const int deg = offsets[n + 1] - off;

    const float bf = lin_b[c], bc = lin_b[c + 16];
    float macc[4][4] = {{0.f}};

    float zv[16];
    if (deg > 0) {
        const float* zp = zc + (size_t)bucket_tgt[off] * 1024;
        #pragma unroll
        for (int k = 0; k < 16; ++k) zv[k] = zp[k * 64 + lane];
    }

    for (int it = 0; it < deg; ++it) {
        float a[16];
        #pragma unroll
        for (int k = 0; k < 16; ++k) a[k] = felu(nv[k] * zv[k]);
        unsigned h[8], l[8];
        #pragma unroll
        for (int d = 0; d < 8; ++d) split2(a[2 * d], a[2 * d + 1], h[d], l[d]);
        *(uint4*)&zb[sbase]      = make_uint4(h[0], h[1], h[2], h[3]);
        *(uint4*)&zb[sbase + 4]  = make_uint4(h[4], h[5], h[6], h[7]);
        *(uint4*)&zb[sbase + 8]  = make_uint4(l[0], l[1], l[2], l[3]);
        *(uint4*)&zb[sbase + 12] = make_uint4(l[4], l[5], l[6], l[7]);

        if (it + 1 < deg) {                  // prefetch next edge during MFMA
            const float* zp = zc + (size_t)bucket_tgt[off + it + 1] * 1024;
            #pragma unroll
            for (int k = 0; k < 16; ++k) zv[k] = zp[k * 64 + lane];
        }

        #pragma unroll
        for (int mt = 0; mt < 4; ++mt) {
            floatx4 a0 = {0.f, 0.f, 0.f, 0.f}, a1 = {0.f, 0.f, 0.f, 0.f};
            const int mb = mt * 2 * 10 * PITCH;
            #pragma unroll
            for (int s = 0; s < 5; ++s) {
                short8 Ah = *(const short8*)&zb[mb + aoff[s]];
                short8 Al = *(const short8*)&zb[mb + aoff[s] + 8];
                a0 = __builtin_amdgcn_mfma_f32_16x16x32_bf16(Ah, W[0][0][s], a0, 0, 0, 0);
                a1 = __builtin_amdgcn_mfma_f32_16x16x32_bf16(Ah, W[0][1][s], a1, 0, 0, 0);
                a0 = __builtin_amdgcn_mfma_f32_16x16x32_bf16(Al, W[0][0][s], a0, 0, 0, 0);
                a1 = __builtin_amdgcn_mfma_f32_16x16x32_bf16(Al, W[0][1][s], a1, 0, 0, 0);
                a0 = __builtin_amdgcn_mfma_f32_16x16x32_bf16(Ah, W[1][0][s], a0, 0, 0, 0);
                a1 = __builtin_amdgcn_mfma_f32_16x16x32_bf16(Ah, W[1][1][s], a1, 0, 0, 0);
            }
            #pragma unroll
            for (int r = 0; r < 4; ++r)
                macc[mt][r] += fsigmoid(a0[r] + bf) * fsoftplus(a1[r] + bc);
        }
    }

    // fused BN + softplus epilogue; pixel = mt*16 + q*4 + r, cout = c
    const float scale = gamma[c] * (1.f / sqrtf(1.f + 1e-5f));
    const float bet = beta[c];
    #pragma unroll
    for (int mt = 0; mt < 4; ++mt) {
        const size_t ob = nb + (size_t)c * 64 + mt * 16 + q * 4;
        const float4 av = *(const float4*)&atom[ob];
        float av4[4] = {av.x, av.y, av.z, av.w};
        float4 ov;
        float ov4[4];
        #pragma unroll
        for (int r = 0; r < 4; ++r) {
            float aa = av4[r];
            ov4[r] = fsoftplus(aa + (aa + macc[mt][r]) * scale + bet);
        }
        ov.x = ov4[0]; ov.y = ov4[1]; ov.z = ov4[2]; ov.w = ov4[3];
        *(float4*)&out[ob] = ov;
    }
}

extern "C" void kernel_launch(void* const* d_in, const int* in_sizes, int n_in,
                              void* d_out, int out_size, void* d_ws, size_t ws_size,
                              hipStream_t stream) {
    const float* atom   = (const float*)d_in[0];
    const int*   esrc   = (const int*)d_in[1];
    const int*   etgt   = (const int*)d_in[2];
    const float* edge_w = (const float*)d_in[3];
    const float* node_w = (const float*)d_in[4];
    const float* lin_w  = (const float*)d_in[5];
    const float* lin_b  = (const float*)d_in[6];
    const float* gamma  = (const float*)d_in[7];
    const float* beta   = (const float*)d_in[8];
    float* out = (float*)d_out;

    const int total = in_sizes[0];      // N*16*8*8
    const int N = total / 1024;         // 8000
    const int E = in_sizes[1];          // 48000

    char* wsb = (char*)d_ws;
    float* zcb       = (float*)wsb;                                   // total fp32
    float* ncb       = (float*)(wsb + (size_t)total * 4);             // total fp32
    short* wfrag_lin = (short*)(wsb + (size_t)total * 8);             // 10240 (16B-aligned)
    short* wfrag_nod = wfrag_lin + 10240;                             // 10240
    int*   counts    = (int*)(wfrag_nod + 10240);                     // N
    int*   cursor    = counts + N;                                    // N
    int*   offsets   = cursor + N;                                    // N+1
    int*   bucket    = offsets + N + 1;                               // E
    int*   nlist     = bucket + E;                                    // N

    const int nhist = (E + 255) / 256;
    const int nconv = (N + 3) / 4;

    hipMemsetAsync(counts, 0, (size_t)2 * N * 4, stream);             // counts+cursor
    prep_hist_kernel<<<nhist + 1, 256, 0, stream>>>(
        edge_w, node_w, lin_w, esrc, wfrag_lin, wfrag_nod, counts, E, nhist);
    scan_kernel<<<1, 256, 0, stream>>>(counts, offsets, N);
    conv_scatter_order_kernel<<<nconv + nhist + 1, 256, 0, stream>>>(
        atom, wfrag_nod, zcb, ncb, esrc, etgt, offsets, cursor, bucket, nlist,
        N, E, nconv, nhist);
    node_edge_kernel<<<nconv, 256, 0, stream>>>(
        atom, zcb, ncb, offsets, bucket, nlist, wfrag_lin, lin_b, gamma, beta, out, N);
}